// Round 3
// baseline (1218.076 us; speedup 1.0000x reference)
//
#include <hip/hip_runtime.h>
#include <hip/hip_bf16.h>
#include <math.h>

#define BQ   2      // batch
#define NN   1024   // seq len
#define DMD  512    // d_model
#define NH   8      // heads
#define DKK  64     // head dim
#define NSEL 5      // NB+1 block values (0..4)
#define NCLS 17     // block-pair classes
#define NP   1344   // padded per-batch capacity (buckets padded to 64)
#define NPT  21     // NP/64 tiles

__device__ __forceinline__ int clsOf(int r, int c) { return (r == 0 || c == 0) ? 0 : ((r - 1) * 4 + c); }

// load float element i from a buffer that is bf16 (isbf=1) or f32 (isbf=0)
__device__ __forceinline__ float ldf(const void* p, size_t i, int isbf) {
    return isbf ? __bfloat162float(((const __hip_bfloat16*)p)[i])
                : ((const float*)p)[i];
}

// 1 => bf16 array, 0 => f32 array. Probes low-half uint16s of the first 64
// 4-byte-if-f32 elements: true-bf16 has plausible exponents everywhere;
// f32 random mantissas fail (p_all_pass ~ 1e-48); f32-upcast-of-bf16
// (zero low halves) is classified f32 via the zero count.
__device__ int det_bf16(const void* p) {
    const unsigned short* u = (const unsigned short*)p;
    int oklo = 0, zlo = 0;
    for (int i = 0; i < 64; i++) {
        unsigned short lo = u[2 * i];
        int e = (lo >> 7) & 0xFF;
        if ((lo & 0x7FFF) == 0) zlo++;
        if ((lo & 0x7FFF) == 0 || (e >= 90 && e <= 135)) oklo++;
    }
    if (zlo >= 32) return 0;
    return (oklo >= 60) ? 1 : 0;
}

// ---------------------------------------------------------------- setup
__global__ __launch_bounds__(256) void k_setup(
    const void* __restrict__ b_seq_r, const void* __restrict__ mask_r,
    const void* __restrict__ al1, const void* __restrict__ al2,
    const void* __restrict__ qr, const void* __restrict__ kr,
    const void* __restrict__ vr, const void* __restrict__ lr,
    const void* __restrict__ w1r, const void* __restrict__ w2r,
    int* __restrict__ maskI, int* __restrict__ perm, int* __restrict__ rowc,
    int* __restrict__ startPad, int* __restrict__ flagsOut,
    float* __restrict__ sm1, float* __restrict__ sm2)
{
    __shared__ int sf[10];
    __shared__ int cnts[BQ][NSEL];
    __shared__ int offs[BQ][NSEL];
    __shared__ int sstart[BQ][NSEL + 1];
    int tid = threadIdx.x;
    if (tid < BQ * NSEL) { cnts[tid / NSEL][tid % NSEL] = 0; offs[tid / NSEL][tid % NSEL] = 0; }
    if (tid == 0) {
        sf[0] = det_bf16(qr);  sf[1] = det_bf16(kr);
        sf[2] = det_bf16(vr);  sf[3] = det_bf16(lr);
        sf[4] = det_bf16(w1r); sf[5] = det_bf16(al1);
        sf[6] = det_bf16(w2r); sf[7] = det_bf16(al2);
        // b_seq: int64? (values 0..4 -> high words all zero)
        const int* b32 = (const int*)b_seq_r;
        int oddnz = 0, evennz = 0;
        for (int i = 0; i < 64; i++) { if (b32[2 * i + 1] != 0) oddnz++; if (b32[2 * i] != 0) evennz++; }
        sf[8] = (oddnz == 0 && evennz > 0) ? 1 : 0;
        // mask kind: 1=byte bool, 0=int32, 2=int64
        const unsigned char* mb = (const unsigned char*)mask_r;
        int bytenz = 0;
        for (int i = 0; i < 256; i++) if ((i & 3) != 0 && mb[i] != 0) bytenz++;
        if (bytenz > 0) sf[9] = 1;
        else {
            const int* m32 = (const int*)mask_r;
            int onz = 0, enz = 0;
            for (int i = 0; i < 64; i++) { if (m32[2 * i + 1] != 0) onz++; if (m32[2 * i] != 0) enz++; }
            sf[9] = (onz == 0 && enz > 0) ? 2 : 0;
        }
        for (int i = 0; i < 10; i++) flagsOut[i] = sf[i];
    }
    __syncthreads();
    int bsI64 = sf[8], mk = sf[9];
    const int* b32 = (const int*)b_seq_r;
    const unsigned char* mb = (const unsigned char*)mask_r;
    const int* m32 = (const int*)mask_r;

    for (int g = tid; g < BQ * NN; g += 256) {
        int m = (mk == 1) ? (mb[g] != 0) : ((mk == 2) ? (m32[2 * g] != 0) : (m32[g] != 0));
        maskI[g] = m;
        int bs = bsI64 ? b32[2 * g] : b32[g];
        bs = bs < 0 ? 0 : (bs > 4 ? 4 : bs);
        atomicAdd(&cnts[g / NN][bs], 1);
    }
    __syncthreads();
    if (tid == 0) {
        for (int b = 0; b < BQ; b++) {
            int acc = 0;
            for (int c = 0; c < NSEL; c++) {
                sstart[b][c] = acc;
                acc += ((cnts[b][c] + 63) / 64) * 64;
            }
            sstart[b][NSEL] = acc;
            for (int c = 0; c <= NSEL; c++) startPad[b * (NSEL + 1) + c] = sstart[b][c];
        }
    }
    __syncthreads();
    for (int g = tid; g < BQ * NP; g += 256) {
        perm[g] = -1;
        int b = g / NP, sslot = g % NP;
        int c = 0;
        for (int cc = 1; cc < NSEL; cc++) if (sslot >= sstart[b][cc]) c = cc;
        rowc[g] = c;
    }
    __syncthreads();
    for (int g = tid; g < BQ * NN; g += 256) {
        int b = g / NN, n = g % NN;
        int bs = bsI64 ? b32[2 * g] : b32[g];
        bs = bs < 0 ? 0 : (bs > 4 ? 4 : bs);
        int pos = sstart[b][bs] + atomicAdd(&offs[b][bs], 1);
        perm[b * NP + pos] = n;
    }
    // alpha softmaxes over the 4 blocks
    for (int p = tid; p < 2 * NCLS * NH; p += 256) {
        int w = p / (NCLS * NH);
        int rem = p % (NCLS * NH);
        int c = rem / NH, h = rem % NH;
        const void* a = w ? al2 : al1;
        int fa = w ? sf[7] : sf[5];
        float vals[4], mx = -1e30f;
        for (int bb = 0; bb < 4; bb++) { vals[bb] = ldf(a, (size_t)(c * 4 + bb) * NH + h, fa); mx = fmaxf(mx, vals[bb]); }
        float ssum = 0.f;
        for (int bb = 0; bb < 4; bb++) { vals[bb] = expf(vals[bb] - mx); ssum += vals[bb]; }
        float inv = 1.0f / ssum;
        float* dst = w ? sm2 : sm1;
        for (int bb = 0; bb < 4; bb++) dst[(c * 4 + bb) * NH + h] = vals[bb] * inv;
    }
}

// ---------------------------------------------------------------- W mixing: W1m/W2m [17][8][64][64] f32
__global__ __launch_bounds__(256) void k_wmix(
    const void* __restrict__ W1, const void* __restrict__ W2, const int* __restrict__ flags,
    const float* __restrict__ sm1, const float* __restrict__ sm2,
    float* __restrict__ W1m, float* __restrict__ W2m)
{
    int bid = blockIdx.x;                 // 0..2*17*8-1
    int w = bid / (NCLS * NH);
    int rem = bid % (NCLS * NH);
    int c = rem / NH, h = rem % NH;
    const void* W = w ? W2 : W1;
    int f = flags[w ? 6 : 4];
    const float* sm = w ? sm2 : sm1;
    float* out = w ? W2m : W1m;
    float s0 = sm[(c * 4 + 0) * NH + h], s1 = sm[(c * 4 + 1) * NH + h];
    float s2 = sm[(c * 4 + 2) * NH + h], s3 = sm[(c * 4 + 3) * NH + h];
    for (int e = threadIdx.x; e < 64 * 64; e += 256) {
        float v = s0 * ldf(W, (size_t)(0 * NH + h) * 4096 + e, f)
                + s1 * ldf(W, (size_t)(1 * NH + h) * 4096 + e, f)
                + s2 * ldf(W, (size_t)(2 * NH + h) * 4096 + e, f)
                + s3 * ldf(W, (size_t)(3 * NH + h) * 4096 + e, f);
        out[((size_t)c * NH + h) * 4096 + e] = v;
    }
}

// ---------------------------------------------------------------- bucketed QKV projection
// grid (21 tiles, 4 hk-quarters, B*3), block 256. Tile: 64 permuted rows x 128 hk.
__global__ __launch_bounds__(256) void k_proj(
    const void* __restrict__ qr, const void* __restrict__ kr, const void* __restrict__ vr,
    const void* __restrict__ lr, const int* __restrict__ flags,
    const int* __restrict__ perm, const int* __restrict__ rowc, const int* __restrict__ startPad,
    float* __restrict__ Qp, float* __restrict__ Vp, float* __restrict__ KT)
{
    int ti = blockIdx.x;
    int qtr = blockIdx.y;
    int bt = blockIdx.z;
    int b = bt / 3, t = bt % 3;
    int nTot = startPad[b * (NSEL + 1) + NSEL];
    if (ti * 64 >= nTot) return;
    int sel = rowc[b * NP + ti * 64];     // uniform per 64-tile by construction
    int fX = flags[t], fL = flags[3];
    const void* X = (t == 0) ? qr : ((t == 1) ? kr : vr);
    size_t Lbase = ((size_t)t * NSEL + sel) * DMD * 512;

    __shared__ __align__(16) char smem[33280];
    float (*Xs)[33]  = (float (*)[33])smem;
    float (*Ls)[128] = (float (*)[128])(smem + 64 * 33 * 4);
    float (*Ts)[65]  = (float (*)[65])smem;     // aliases Xs/Ls; used after compute
    __shared__ int toks[64];

    int tid = threadIdx.x;
    int tr = tid >> 5, tc = tid & 31;
    if (tid < 64) toks[tid] = perm[b * NP + ti * 64 + tid];
    float acc[8][4];
#pragma unroll
    for (int rr = 0; rr < 8; rr++) { acc[rr][0] = 0; acc[rr][1] = 0; acc[rr][2] = 0; acc[rr][3] = 0; }
    __syncthreads();

    for (int d0 = 0; d0 < DMD; d0 += 32) {
#pragma unroll
        for (int i = 0; i < 8; i++) {
            int idx = tid + i * 256;           // 2048 = 64 rows x 32 d
            int row = idx >> 5, dd = idx & 31;
            int tok = toks[row];
            Xs[row][dd] = (tok >= 0) ? ldf(X, ((size_t)b * NN + tok) * DMD + d0 + dd, fX) : 0.f;
        }
#pragma unroll
        for (int i = 0; i < 16; i++) {
            int idx = tid + i * 256;           // 4096 = 32 d x 128 cols
            int dd = idx >> 7, col = idx & 127;
            Ls[dd][col] = ldf(lr, Lbase + (size_t)(d0 + dd) * 512 + qtr * 128 + col, fL);
        }
        __syncthreads();
        for (int dd = 0; dd < 32; dd++) {
            float4 lv = *(const float4*)&Ls[dd][tc * 4];
#pragma unroll
            for (int rr = 0; rr < 8; rr++) {
                float xv = Xs[tr * 8 + rr][dd];
                acc[rr][0] += xv * lv.x; acc[rr][1] += xv * lv.y;
                acc[rr][2] += xv * lv.z; acc[rr][3] += xv * lv.w;
            }
        }
        __syncthreads();
    }

    if (t == 1) {
        // write K transposed: KT[b][h][k][ip]
#pragma unroll
        for (int rr = 0; rr < 8; rr++)
#pragma unroll
            for (int cc = 0; cc < 4; cc++)
                Ts[tc * 4 + cc][tr * 8 + rr] = acc[rr][cc];
        __syncthreads();
#pragma unroll
        for (int i = 0; i < 32; i++) {
            int idx = tid + i * 256;           // 8192 = 128 hk x 64 ip
            int ip = idx & 63, hkl = idx >> 6;
            int hk = qtr * 128 + hkl;
            int h = hk >> 6, k = hk & 63;
            KT[(((size_t)b * NH + h) * DKK + k) * NP + ti * 64 + ip] = Ts[hkl][ip];
        }
    } else {
        float* O = (t == 0) ? Qp : Vp;
#pragma unroll
        for (int rr = 0; rr < 8; rr++) {
            int ip = ti * 64 + tr * 8 + rr;
            int hk0 = qtr * 128 + tc * 4;
            int h = hk0 >> 6, k0 = hk0 & 63;
            float4 v4; v4.x = acc[rr][0]; v4.y = acc[rr][1]; v4.z = acc[rr][2]; v4.w = acc[rr][3];
            *(float4*)&O[(((size_t)b * NH + h) * NP + ip) * DKK + k0] = v4;
        }
    }
}

// ---------------------------------------------------------------- fused attention
// grid (NP/8, B*H), block 256 (4 waves). 8 query rows per block (bucket-uniform).
__global__ __launch_bounds__(256) void k_attn(
    const float* __restrict__ Qp, const float* __restrict__ Vp, const float* __restrict__ KT,
    const float* __restrict__ W1m, const float* __restrict__ W2m,
    const int* __restrict__ perm, const int* __restrict__ rowc, const int* __restrict__ startPad,
    const int* __restrict__ maskI, float* __restrict__ out)
{
    int ib = blockIdx.x;
    int bh = blockIdx.y;
    int b = bh >> 3, h = bh & 7;
    int nTot = startPad[b * (NSEL + 1) + NSEL];
    int i0 = ib * 8;
    if (i0 >= nTot) return;
    int r = rowc[b * NP + i0];
    int tiles = nTot >> 6;

    __shared__ float s[8][NP];                  // score rows / later scratch
    __shared__ float qloc[NSEL * 8 * DKK];      // Q' variants / later u accumulator
    __shared__ float qrows[8][DKK];
    __shared__ int mrow[8];
    __shared__ int toki[8];

    int tid = threadIdx.x;
    int wave = tid >> 6, lane = tid & 63;
    const int* permB = perm + b * NP;
    const float* QpB = Qp + ((size_t)b * NH + h) * NP * DKK;
    const float* VpB = Vp + ((size_t)b * NH + h) * NP * DKK;
    const float* KTB = KT + ((size_t)b * NH + h) * DKK * NP;

    // ---- phase 0a: stage q rows + row masks
    for (int e = tid; e < 8 * DKK; e += 256) {
        int rr = e >> 6, k = e & 63;
        qrows[rr][k] = QpB[(size_t)(i0 + rr) * DKK + k];
    }
    if (tid < 8) {
        int tok = permB[i0 + tid];
        toki[tid] = tok;
        mrow[tid] = (tok >= 0) ? maskI[b * NN + tok] : 0;
    }
    __syncthreads();

    // ---- phase 0b: qloc[c][rr][n] = sum_m qrows[rr][m] * W1m[cls(r,c)][h][m][n]
    for (int oi = tid; oi < NSEL * 64; oi += 256) {
        int c = oi >> 6, n = oi & 63;
        int cls = clsOf(r, c);
        const float* Wp = W1m + ((size_t)cls * NH + h) * 4096 + n;
        float a[8] = {0, 0, 0, 0, 0, 0, 0, 0};
        for (int m = 0; m < 64; m++) {
            float wv = Wp[(size_t)m * 64];
#pragma unroll
            for (int rr = 0; rr < 8; rr++) a[rr] += qrows[rr][m] * wv;
        }
#pragma unroll
        for (int rr = 0; rr < 8; rr++) qloc[(c * 8 + rr) * 64 + n] = a[rr];
    }
    __syncthreads();

    // ---- phase 1: scores (each wave takes whole 64-wide key tiles; lane = j within tile)
    for (int jt = wave; jt < tiles; jt += 4) {
        int c = rowc[b * NP + jt * 64];
        int j = jt * 64 + lane;
        int tok = permB[j];
        int mj = (tok >= 0) ? maskI[b * NN + tok] : 0;
        float acc[8] = {0, 0, 0, 0, 0, 0, 0, 0};
        const float* ql = qloc + c * 512;
        for (int kk = 0; kk < 64; kk += 4) {
            float kv0 = KTB[(size_t)(kk + 0) * NP + j];
            float kv1 = KTB[(size_t)(kk + 1) * NP + j];
            float kv2 = KTB[(size_t)(kk + 2) * NP + j];
            float kv3 = KTB[(size_t)(kk + 3) * NP + j];
#pragma unroll
            for (int rr = 0; rr < 8; rr++) {
                float4 q4 = *(const float4*)&ql[rr * 64 + kk];
                acc[rr] += q4.x * kv0 + q4.y * kv1 + q4.z * kv2 + q4.w * kv3;
            }
        }
#pragma unroll
        for (int rr = 0; rr < 8; rr++) {
            float sv;
            if (tok < 0)                sv = -INFINITY;       // padding slot
            else if (mrow[rr] && mj)    sv = acc[rr] * 0.125f;
            else                        sv = -1e30f;          // reference's masked value
            s[rr][j] = sv;
        }
    }
    __syncthreads();

    // ---- phase 2: softmax per row (wave w owns rows 2w, 2w+1)
    for (int rr = wave * 2; rr < wave * 2 + 2; rr++) {
        float m = -INFINITY;
        for (int j = lane; j < nTot; j += 64) m = fmaxf(m, s[rr][j]);
        for (int o = 32; o > 0; o >>= 1) m = fmaxf(m, __shfl_xor(m, o));
        float sum = 0.f;
        for (int j = lane; j < nTot; j += 64) {
            float e = expf(s[rr][j] - m);
            s[rr][j] = e;
            sum += e;
        }
        for (int o = 32; o > 0; o >>= 1) sum += __shfl_xor(sum, o);
        float inv = 1.0f / sum;
        for (int j = lane; j < nTot; j += 64) s[rr][j] *= inv;
    }
    __syncthreads();

    // ---- phase 3: per-bucket PV partials (lane = d), register accumulators
    float au[NSEL][8];
#pragma unroll
    for (int c = 0; c < NSEL; c++)
#pragma unroll
        for (int rr = 0; rr < 8; rr++) au[c][rr] = 0.f;

#define PV_TILE(C)                                                              \
    for (int jj = 0; jj < 64; jj++) {                                           \
        int j = jb + jj;                                                        \
        float v = VpB[(size_t)j * DKK + lane];                                  \
        _Pragma("unroll")                                                       \
        for (int rr = 0; rr < 8; rr++) au[C][rr] += s[rr][j] * v;               \
    }

    for (int jt = wave; jt < tiles; jt += 4) {
        int c = rowc[b * NP + jt * 64];
        int jb = jt * 64;
        switch (c) {
            case 0: PV_TILE(0) break;
            case 1: PV_TILE(1) break;
            case 2: PV_TILE(2) break;
            case 3: PV_TILE(3) break;
            default: PV_TILE(4) break;
        }
    }
#undef PV_TILE

    // cross-wave reduction into u (reuses qloc)
    float* u = qloc;
    for (int w = 0; w < 4; w++) {
        if (wave == w) {
#pragma unroll
            for (int c = 0; c < NSEL; c++)
#pragma unroll
                for (int rr = 0; rr < 8; rr++) {
                    int idx = (c * 8 + rr) * 64 + lane;
                    if (w == 0) u[idx] = au[c][rr];
                    else        u[idx] += au[c][rr];
                }
        }
        __syncthreads();
    }

    // ---- phase 4: out[rr][k] = sum_c sum_d u[c][rr][d] * W2m[cls(r,c)][h][d][k]
    float* scratch = &s[0][0];   // s is dead now; 5*8*64 floats fit easily
    for (int oi = tid; oi < NSEL * 64; oi += 256) {
        int c = oi >> 6, k = oi & 63;
        int cls = clsOf(r, c);
        const float* Wp = W2m + ((size_t)cls * NH + h) * 4096 + k;
        float a[8] = {0, 0, 0, 0, 0, 0, 0, 0};
        for (int d = 0; d < 64; d++) {
            float wv = Wp[(size_t)d * 64];
#pragma unroll
            for (int rr = 0; rr < 8; rr++) a[rr] += u[(c * 8 + rr) * 64 + d] * wv;
        }
#pragma unroll
        for (int rr = 0; rr < 8; rr++) scratch[(c * 8 + rr) * 64 + k] = a[rr];
    }
    __syncthreads();
    for (int oi = tid; oi < 512; oi += 256) {
        int rr = oi >> 6, k = oi & 63;
        int tok = toki[rr];
        if (tok >= 0) {
            float a = 0.f;
#pragma unroll
            for (int c = 0; c < NSEL; c++) a += scratch[(c * 8 + rr) * 64 + k];
            out[((size_t)b * NN + tok) * (NH * DKK) + h * DKK + k] = a;   // f32 output
        }
    }
}

// ---------------------------------------------------------------- launch
extern "C" void kernel_launch(void* const* d_in, const int* in_sizes, int n_in,
                              void* d_out, int out_size, void* d_ws, size_t ws_size,
                              hipStream_t stream)
{
    const void* qr   = d_in[0];
    const void* kr   = d_in[1];
    const void* vr   = d_in[2];
    const void* bsr  = d_in[3];
    const void* mkr  = d_in[4];
    const void* lr   = d_in[5];
    const void* w1r  = d_in[6];
    const void* a1r  = d_in[7];
    const void* w2r  = d_in[8];
    const void* a2r  = d_in[9];
    float* out = (float*)d_out;   // reference output dtype is float32

    char* w = (char*)d_ws;
    int* maskI    = (int*)w;                       // 2048 ints
    int* perm     = maskI + BQ * NN;               // 2688 ints
    int* rowc     = perm + BQ * NP;                // 2688 ints
    int* startPad = rowc + BQ * NP;                // 12 ints
    int* flags    = startPad + 12;                 // 16 ints
    float* sm1 = (float*)(w + 32768);
    float* sm2 = sm1 + NCLS * 4 * NH;
    float* W1m = sm2 + NCLS * 4 * NH;
    float* W2m = W1m + (size_t)NCLS * NH * 4096;
    float* Qp  = W2m + (size_t)NCLS * NH * 4096;
    float* Vp  = Qp + (size_t)BQ * NH * NP * DKK;
    float* KT  = Vp + (size_t)BQ * NH * NP * DKK;
    // total ws use: ~21 MB

    hipLaunchKernelGGL(k_setup, dim3(1), dim3(256), 0, stream,
                       bsr, mkr, a1r, a2r, qr, kr, vr, lr, w1r, w2r,
                       maskI, perm, rowc, startPad, flags, sm1, sm2);
    hipLaunchKernelGGL(k_wmix, dim3(2 * NCLS * NH), dim3(256), 0, stream,
                       w1r, w2r, flags, sm1, sm2, W1m, W2m);
    hipLaunchKernelGGL(k_proj, dim3(NPT, 4, 6), dim3(256), 0, stream,
                       qr, kr, vr, lr, flags, perm, rowc, startPad, Qp, Vp, KT);
    hipLaunchKernelGGL(k_attn, dim3(NP / 8, BQ * NH), dim3(256), 0, stream,
                       Qp, Vp, KT, W1m, W2m, perm, rowc, startPad, maskI, out);
}

// Round 4
// 539.372 us; speedup vs baseline: 2.2583x; 2.2583x over previous
//
#include <hip/hip_runtime.h>
#include <hip/hip_bf16.h>
#include <math.h>

#define BQ   2      // batch
#define NN   1024   // seq len
#define DMD  512    // d_model
#define NH   8      // heads
#define DKK  64     // head dim
#define NSEL 5      // NB+1 block values (0..4)
#define NCLS 17     // block-pair classes
#define NP   1344   // padded per-batch capacity (buckets padded to 64)
#define NPT  21     // NP/64 tiles

__device__ __forceinline__ int clsOf(int r, int c) { return (r == 0 || c == 0) ? 0 : ((r - 1) * 4 + c); }

// ---------------------------------------------------------------- setup
// All float inputs PROVEN f32 (round-1 bf16-read NaN'd; round-3 f32-read passed
// at absmax 3.9e-3). Only b_seq/mask integer width still auto-detected.
__global__ __launch_bounds__(256) void k_setup(
    const void* __restrict__ b_seq_r, const void* __restrict__ mask_r,
    const float* __restrict__ al1, const float* __restrict__ al2,
    int* __restrict__ maskI, int* __restrict__ perm, int* __restrict__ rowc,
    int* __restrict__ startPad, float* __restrict__ sm1, float* __restrict__ sm2)
{
    __shared__ int sf[2];
    __shared__ int cnts[BQ][NSEL];
    __shared__ int offs[BQ][NSEL];
    __shared__ int sstart[BQ][NSEL + 1];
    int tid = threadIdx.x;
    if (tid < BQ * NSEL) { cnts[tid / NSEL][tid % NSEL] = 0; offs[tid / NSEL][tid % NSEL] = 0; }
    if (tid == 0) {
        // b_seq: int64? (values 0..4 -> high words all zero)
        const int* b32 = (const int*)b_seq_r;
        int oddnz = 0, evennz = 0;
        for (int i = 0; i < 64; i++) { if (b32[2 * i + 1] != 0) oddnz++; if (b32[2 * i] != 0) evennz++; }
        sf[0] = (oddnz == 0 && evennz > 0) ? 1 : 0;
        // mask kind: 1=byte bool, 0=int32, 2=int64
        const unsigned char* mb = (const unsigned char*)mask_r;
        int bytenz = 0;
        for (int i = 0; i < 256; i++) if ((i & 3) != 0 && mb[i] != 0) bytenz++;
        if (bytenz > 0) sf[1] = 1;
        else {
            const int* m32 = (const int*)mask_r;
            int onz = 0, enz = 0;
            for (int i = 0; i < 64; i++) { if (m32[2 * i + 1] != 0) onz++; if (m32[2 * i] != 0) enz++; }
            sf[1] = (onz == 0 && enz > 0) ? 2 : 0;
        }
    }
    __syncthreads();
    int bsI64 = sf[0], mk = sf[1];
    const int* b32 = (const int*)b_seq_r;
    const unsigned char* mb = (const unsigned char*)mask_r;
    const int* m32 = (const int*)mask_r;

    for (int g = tid; g < BQ * NN; g += 256) {
        int m = (mk == 1) ? (mb[g] != 0) : ((mk == 2) ? (m32[2 * g] != 0) : (m32[g] != 0));
        maskI[g] = m;
        int bs = bsI64 ? b32[2 * g] : b32[g];
        bs = bs < 0 ? 0 : (bs > 4 ? 4 : bs);
        atomicAdd(&cnts[g / NN][bs], 1);
    }
    __syncthreads();
    if (tid == 0) {
        for (int b = 0; b < BQ; b++) {
            int acc = 0;
            for (int c = 0; c < NSEL; c++) {
                sstart[b][c] = acc;
                acc += ((cnts[b][c] + 63) / 64) * 64;
            }
            sstart[b][NSEL] = acc;
            for (int c = 0; c <= NSEL; c++) startPad[b * (NSEL + 1) + c] = sstart[b][c];
        }
    }
    __syncthreads();
    for (int g = tid; g < BQ * NP; g += 256) {
        perm[g] = -1;
        int b = g / NP, sslot = g % NP;
        int c = 0;
        for (int cc = 1; cc < NSEL; cc++) if (sslot >= sstart[b][cc]) c = cc;
        rowc[g] = c;
    }
    __syncthreads();
    for (int g = tid; g < BQ * NN; g += 256) {
        int b = g / NN, n = g % NN;
        int bs = bsI64 ? b32[2 * g] : b32[g];
        bs = bs < 0 ? 0 : (bs > 4 ? 4 : bs);
        int pos = sstart[b][bs] + atomicAdd(&offs[b][bs], 1);
        perm[b * NP + pos] = n;
    }
    // alpha softmaxes over the 4 blocks
    for (int p = tid; p < 2 * NCLS * NH; p += 256) {
        int w = p / (NCLS * NH);
        int rem = p % (NCLS * NH);
        int c = rem / NH, h = rem % NH;
        const float* a = w ? al2 : al1;
        float vals[4], mx = -1e30f;
        for (int bb = 0; bb < 4; bb++) { vals[bb] = a[(c * 4 + bb) * NH + h]; mx = fmaxf(mx, vals[bb]); }
        float ssum = 0.f;
        for (int bb = 0; bb < 4; bb++) { vals[bb] = expf(vals[bb] - mx); ssum += vals[bb]; }
        float inv = 1.0f / ssum;
        float* dst = w ? sm2 : sm1;
        for (int bb = 0; bb < 4; bb++) dst[(c * 4 + bb) * NH + h] = vals[bb] * inv;
    }
}

// ---------------------------------------------------------------- W mixing: W1m/W2m [17][8][64][64] f32
__global__ __launch_bounds__(256) void k_wmix(
    const float* __restrict__ W1, const float* __restrict__ W2,
    const float* __restrict__ sm1, const float* __restrict__ sm2,
    float* __restrict__ W1m, float* __restrict__ W2m)
{
    int bid = blockIdx.x;                 // 0..2*17*8-1
    int w = bid / (NCLS * NH);
    int rem = bid % (NCLS * NH);
    int c = rem / NH, h = rem % NH;
    const float* W = w ? W2 : W1;
    const float* sm = w ? sm2 : sm1;
    float* out = w ? W2m : W1m;
    float s0 = sm[(c * 4 + 0) * NH + h], s1 = sm[(c * 4 + 1) * NH + h];
    float s2 = sm[(c * 4 + 2) * NH + h], s3 = sm[(c * 4 + 3) * NH + h];
    const float4* W0 = (const float4*)(W + (size_t)(0 * NH + h) * 4096);
    const float4* Wa = (const float4*)(W + (size_t)(1 * NH + h) * 4096);
    const float4* Wb = (const float4*)(W + (size_t)(2 * NH + h) * 4096);
    const float4* Wc = (const float4*)(W + (size_t)(3 * NH + h) * 4096);
    float4* O = (float4*)(out + ((size_t)c * NH + h) * 4096);
    for (int e = threadIdx.x; e < 1024; e += 256) {
        float4 a = W0[e], bq = Wa[e], cq = Wb[e], d = Wc[e];
        float4 v;
        v.x = s0 * a.x + s1 * bq.x + s2 * cq.x + s3 * d.x;
        v.y = s0 * a.y + s1 * bq.y + s2 * cq.y + s3 * d.y;
        v.z = s0 * a.z + s1 * bq.z + s2 * cq.z + s3 * d.z;
        v.w = s0 * a.w + s1 * bq.w + s2 * cq.w + s3 * d.w;
        O[e] = v;
    }
}

// ---------------------------------------------------------------- bucketed QKV projection (f32)
// grid (21 tiles, 4 hk-quarters, B*3), block 256. Tile: 64 permuted rows x 128 hk.
__global__ __launch_bounds__(256) void k_proj(
    const float* __restrict__ qr, const float* __restrict__ kr, const float* __restrict__ vr,
    const float* __restrict__ lr,
    const int* __restrict__ perm, const int* __restrict__ rowc, const int* __restrict__ startPad,
    float* __restrict__ Qp, float* __restrict__ Vp, float* __restrict__ KT)
{
    int ti = blockIdx.x;
    int qtr = blockIdx.y;
    int bt = blockIdx.z;
    int b = bt / 3, t = bt % 3;
    int nTot = startPad[b * (NSEL + 1) + NSEL];
    if (ti * 64 >= nTot) return;
    int sel = rowc[b * NP + ti * 64];     // uniform per 64-tile by construction
    const float* X = (t == 0) ? qr : ((t == 1) ? kr : vr);
    const float* L = lr + ((size_t)t * NSEL + sel) * DMD * 512;

    __shared__ __align__(16) char smem[33280];
    float (*Xs)[36]  = (float (*)[36])smem;                    // 64x36 = 9216 B
    float (*Ls)[128] = (float (*)[128])(smem + 9216);          // 32x128 = 16384 B
    float (*Ts)[65]  = (float (*)[65])smem;                    // alias, used after compute
    __shared__ int toks[64];

    int tid = threadIdx.x;
    int tr = tid >> 5, tc = tid & 31;
    if (tid < 64) toks[tid] = perm[b * NP + ti * 64 + tid];
    float acc[8][4];
#pragma unroll
    for (int rr = 0; rr < 8; rr++) { acc[rr][0] = 0; acc[rr][1] = 0; acc[rr][2] = 0; acc[rr][3] = 0; }
    __syncthreads();

    for (int d0 = 0; d0 < DMD; d0 += 32) {
        // Xs: 64 rows x 32 d  (512 float4)
#pragma unroll
        for (int i = 0; i < 2; i++) {
            int fidx = tid + i * 256;
            int row = fidx >> 3, q4 = fidx & 7;
            int tok = toks[row];
            float4 val = make_float4(0.f, 0.f, 0.f, 0.f);
            if (tok >= 0) val = *(const float4*)&X[((size_t)b * NN + tok) * DMD + d0 + q4 * 4];
            *(float4*)&Xs[row][q4 * 4] = val;
        }
        // Ls: 32 d x 128 cols (1024 float4)
#pragma unroll
        for (int i = 0; i < 4; i++) {
            int fidx = tid + i * 256;
            int dd = fidx >> 5, c4 = fidx & 31;
            *(float4*)&Ls[dd][c4 * 4] =
                *(const float4*)&L[(size_t)(d0 + dd) * 512 + qtr * 128 + c4 * 4];
        }
        __syncthreads();
#pragma unroll 2
        for (int dd = 0; dd < 32; dd++) {
            float4 lv = *(const float4*)&Ls[dd][tc * 4];
#pragma unroll
            for (int rr = 0; rr < 8; rr++) {
                float xv = Xs[tr * 8 + rr][dd];
                acc[rr][0] += xv * lv.x; acc[rr][1] += xv * lv.y;
                acc[rr][2] += xv * lv.z; acc[rr][3] += xv * lv.w;
            }
        }
        __syncthreads();
    }

    if (t == 1) {
        // write K transposed: KT[b][h][k][ip]
#pragma unroll
        for (int rr = 0; rr < 8; rr++)
#pragma unroll
            for (int cc = 0; cc < 4; cc++)
                Ts[tc * 4 + cc][tr * 8 + rr] = acc[rr][cc];
        __syncthreads();
#pragma unroll
        for (int i = 0; i < 32; i++) {
            int idx = tid + i * 256;           // 8192 = 128 hk x 64 ip
            int ip = idx & 63, hkl = idx >> 6;
            int hk = qtr * 128 + hkl;
            int h = hk >> 6, k = hk & 63;
            KT[(((size_t)b * NH + h) * DKK + k) * NP + ti * 64 + ip] = Ts[hkl][ip];
        }
    } else {
        float* O = (t == 0) ? Qp : Vp;
#pragma unroll
        for (int rr = 0; rr < 8; rr++) {
            int ip = ti * 64 + tr * 8 + rr;
            int hk0 = qtr * 128 + tc * 4;
            int h = hk0 >> 6, k0 = hk0 & 63;
            float4 v4; v4.x = acc[rr][0]; v4.y = acc[rr][1]; v4.z = acc[rr][2]; v4.w = acc[rr][3];
            *(float4*)&O[(((size_t)b * NH + h) * NP + ip) * DKK + k0] = v4;
        }
    }
}

// ---------------------------------------------------------------- fused attention
// grid (NP/8, B*H), block 256 (4 waves). 8 query rows per block (bucket-uniform).
// Spill-free restructure: phase 3 iterates classes sequentially (buckets are
// contiguous) with one au[8] accumulator; per-wave partials reduced via LDS.
__global__ __launch_bounds__(256, 2) void k_attn(
    const float* __restrict__ Qp, const float* __restrict__ Vp, const float* __restrict__ KT,
    const float* __restrict__ W1m, const float* __restrict__ W2m,
    const int* __restrict__ perm, const int* __restrict__ rowc, const int* __restrict__ startPad,
    const int* __restrict__ maskI, float* __restrict__ out)
{
    int ib = blockIdx.x;
    int bh = blockIdx.y;
    int b = bh >> 3, h = bh & 7;
    int nTot = startPad[b * (NSEL + 1) + NSEL];
    int i0 = ib * 8;
    if (i0 >= nTot) return;
    int r = rowc[b * NP + i0];
    int tiles = nTot >> 6;

    __shared__ float s[8][NP];                  // 43008 B: score rows / later scratch
    __shared__ float qloc[NSEL * 8 * DKK];      // 10240 B: Q' variants / later u accumulator
    __shared__ float uw[4][8][DKK];             // 8192 B: per-wave PV partials
    __shared__ float qrows[8][DKK];             // 2048 B
    __shared__ int tilec[NPT];
    __shared__ int cstart[NSEL + 1];
    __shared__ int mrow[8];
    __shared__ int toki[8];

    int tid = threadIdx.x;
    int wave = tid >> 6, lane = tid & 63;
    const int* permB = perm + b * NP;
    const float* QpB = Qp + ((size_t)b * NH + h) * NP * DKK;
    const float* VpB = Vp + ((size_t)b * NH + h) * NP * DKK;
    const float* KTB = KT + ((size_t)b * NH + h) * DKK * NP;

    // ---- phase 0a: stage q rows (float4), tile classes, bucket starts, masks
    if (tid < 128) {
        int row = tid >> 4, q4 = tid & 15;
        *(float4*)&qrows[row][q4 * 4] = *(const float4*)&QpB[(size_t)(i0 + row) * DKK + q4 * 4];
    }
    if (tid >= 128 && tid < 128 + NPT) tilec[tid - 128] = rowc[b * NP + (tid - 128) * 64];
    if (tid >= 160 && tid < 160 + NSEL + 1) cstart[tid - 160] = startPad[b * (NSEL + 1) + (tid - 160)];
    if (tid >= 192 && tid < 200) {
        int rr = tid - 192;
        int tok = permB[i0 + rr];
        toki[rr] = tok;
        mrow[rr] = (tok >= 0) ? maskI[b * NN + tok] : 0;
    }
    __syncthreads();

    // ---- phase 0b: qloc[c][rr][n] = sum_m qrows[rr][m] * W1m[cls(r,c)][h][m][n]
    for (int oi = tid; oi < NSEL * 64; oi += 256) {
        int c = oi >> 6, n = oi & 63;
        int cls = clsOf(r, c);
        const float* Wp = W1m + ((size_t)cls * NH + h) * 4096 + n;
        float a[8] = {0, 0, 0, 0, 0, 0, 0, 0};
#pragma unroll 4
        for (int m = 0; m < 64; m++) {
            float wv = Wp[(size_t)m * 64];
#pragma unroll
            for (int rr = 0; rr < 8; rr++) a[rr] += qrows[rr][m] * wv;
        }
#pragma unroll
        for (int rr = 0; rr < 8; rr++) qloc[(c * 8 + rr) * 64 + n] = a[rr];
    }
    __syncthreads();

    // ---- phase 1: scores (wave takes whole 64-wide key tiles; lane = j within tile)
    for (int jt = wave; jt < tiles; jt += 4) {
        int c = tilec[jt];
        int j = jt * 64 + lane;
        int tok = permB[j];
        int mj = (tok >= 0) ? maskI[b * NN + tok] : 0;
        float acc[8] = {0, 0, 0, 0, 0, 0, 0, 0};
        const float* ql = qloc + c * 512;
#pragma unroll 2
        for (int kk = 0; kk < 64; kk += 4) {
            float kv0 = KTB[(size_t)(kk + 0) * NP + j];
            float kv1 = KTB[(size_t)(kk + 1) * NP + j];
            float kv2 = KTB[(size_t)(kk + 2) * NP + j];
            float kv3 = KTB[(size_t)(kk + 3) * NP + j];
#pragma unroll
            for (int rr = 0; rr < 8; rr++) {
                float4 q4 = *(const float4*)&ql[rr * 64 + kk];
                acc[rr] += q4.x * kv0 + q4.y * kv1 + q4.z * kv2 + q4.w * kv3;
            }
        }
#pragma unroll
        for (int rr = 0; rr < 8; rr++) {
            float sv;
            if (tok < 0)                sv = -INFINITY;       // padding slot
            else if (mrow[rr] && mj)    sv = acc[rr] * 0.125f;
            else                        sv = -1e30f;          // reference's masked value
            s[rr][j] = sv;
        }
    }
    __syncthreads();

    // ---- phase 2: softmax per row (wave w owns rows 2w, 2w+1)
    for (int rr = wave * 2; rr < wave * 2 + 2; rr++) {
        float m = -INFINITY;
        for (int j = lane; j < nTot; j += 64) m = fmaxf(m, s[rr][j]);
        for (int o = 32; o > 0; o >>= 1) m = fmaxf(m, __shfl_xor(m, o));
        float sum = 0.f;
        for (int j = lane; j < nTot; j += 64) {
            float e = expf(s[rr][j] - m);
            s[rr][j] = e;
            sum += e;
        }
        for (int o = 32; o > 0; o >>= 1) sum += __shfl_xor(sum, o);
        float inv = 1.0f / sum;
        for (int j = lane; j < nTot; j += 64) s[rr][j] *= inv;
    }
    __syncthreads();

    // ---- phase 3: PV, one class at a time (contiguous tile ranges), lane = d
    float* u = qloc;                            // qloc is dead; reuse as u[5][8][64]
    for (int c = 0; c < NSEL; c++) {
        int ct0 = cstart[c] >> 6, ct1 = cstart[c + 1] >> 6;
        float au[8] = {0, 0, 0, 0, 0, 0, 0, 0};
        for (int jt = ct0 + wave; jt < ct1; jt += 4) {
            int jb = jt * 64;
#pragma unroll 4
            for (int jj = 0; jj < 64; jj++) {
                float v = VpB[(size_t)(jb + jj) * DKK + lane];
#pragma unroll
                for (int rr = 0; rr < 8; rr++) au[rr] += s[rr][jb + jj] * v;
            }
        }
#pragma unroll
        for (int rr = 0; rr < 8; rr++) uw[wave][rr][lane] = au[rr];
        __syncthreads();
        for (int e = tid; e < 512; e += 256) {
            int rr = e >> 6, d = e & 63;
            u[(c * 8 + rr) * 64 + d] = uw[0][rr][d] + uw[1][rr][d] + uw[2][rr][d] + uw[3][rr][d];
        }
        __syncthreads();
    }

    // ---- phase 4: out[rr][k] = sum_c sum_d u[c][rr][d] * W2m[cls(r,c)][h][d][k]
    float* scratch = &s[0][0];                  // s is dead now
    for (int oi = tid; oi < NSEL * 64; oi += 256) {
        int c = oi >> 6, k = oi & 63;
        int cls = clsOf(r, c);
        const float* Wp = W2m + ((size_t)cls * NH + h) * 4096 + k;
        float a[8] = {0, 0, 0, 0, 0, 0, 0, 0};
#pragma unroll 4
        for (int d = 0; d < 64; d++) {
            float wv = Wp[(size_t)d * 64];
#pragma unroll
            for (int rr = 0; rr < 8; rr++) a[rr] += u[(c * 8 + rr) * 64 + d] * wv;
        }
#pragma unroll
        for (int rr = 0; rr < 8; rr++) scratch[(c * 8 + rr) * 64 + k] = a[rr];
    }
    __syncthreads();
    for (int oi = tid; oi < 512; oi += 256) {
        int rr = oi >> 6, k = oi & 63;
        int tok = toki[rr];
        if (tok >= 0) {
            float a = 0.f;
#pragma unroll
            for (int c = 0; c < NSEL; c++) a += scratch[(c * 8 + rr) * 64 + k];
            out[((size_t)b * NN + tok) * (NH * DKK) + h * DKK + k] = a;   // f32 output
        }
    }
}

// ---------------------------------------------------------------- launch
extern "C" void kernel_launch(void* const* d_in, const int* in_sizes, int n_in,
                              void* d_out, int out_size, void* d_ws, size_t ws_size,
                              hipStream_t stream)
{
    const float* qr  = (const float*)d_in[0];
    const float* kr  = (const float*)d_in[1];
    const float* vr  = (const float*)d_in[2];
    const void* bsr  = d_in[3];
    const void* mkr  = d_in[4];
    const float* lr  = (const float*)d_in[5];
    const float* w1r = (const float*)d_in[6];
    const float* a1r = (const float*)d_in[7];
    const float* w2r = (const float*)d_in[8];
    const float* a2r = (const float*)d_in[9];
    float* out = (float*)d_out;   // reference output dtype is float32

    char* w = (char*)d_ws;
    int* maskI    = (int*)w;                       // 2048 ints
    int* perm     = maskI + BQ * NN;               // 2688 ints
    int* rowc     = perm + BQ * NP;                // 2688 ints
    int* startPad = rowc + BQ * NP;                // 12 ints
    float* sm1 = (float*)(w + 32768);
    float* sm2 = sm1 + NCLS * 4 * NH;
    float* W1m = sm2 + NCLS * 4 * NH;
    float* W2m = W1m + (size_t)NCLS * NH * 4096;
    float* Qp  = W2m + (size_t)NCLS * NH * 4096;
    float* Vp  = Qp + (size_t)BQ * NH * NP * DKK;
    float* KT  = Vp + (size_t)BQ * NH * NP * DKK;
    // total ws use: ~21 MB

    hipLaunchKernelGGL(k_setup, dim3(1), dim3(256), 0, stream,
                       bsr, mkr, a1r, a2r, maskI, perm, rowc, startPad, sm1, sm2);
    hipLaunchKernelGGL(k_wmix, dim3(2 * NCLS * NH), dim3(256), 0, stream,
                       w1r, w2r, sm1, sm2, W1m, W2m);
    hipLaunchKernelGGL(k_proj, dim3(NPT, 4, 6), dim3(256), 0, stream,
                       qr, kr, vr, lr, perm, rowc, startPad, Qp, Vp, KT);
    hipLaunchKernelGGL(k_attn, dim3(NP / 8, BQ * NH), dim3(256), 0, stream,
                       Qp, Vp, KT, W1m, W2m, perm, rowc, startPad, maskI, out);
}

// Round 5
// 295.287 us; speedup vs baseline: 4.1251x; 1.8266x over previous
//
#include <hip/hip_runtime.h>
#include <hip/hip_bf16.h>
#include <math.h>

#define BQ   2      // batch
#define NN   1024   // seq len
#define DMD  512    // d_model
#define NH   8      // heads
#define DKK  64     // head dim
#define NSEL 5      // NB+1 block values (0..4)
#define NCLS 17     // block-pair classes
#define NP   1344   // padded per-batch capacity (buckets padded to 64)
#define NPT  21     // NP/64 tiles

typedef __attribute__((ext_vector_type(8))) short bf16x8;
typedef __attribute__((ext_vector_type(4))) float f32x4;

__device__ __forceinline__ int clsOf(int r, int c) { return (r == 0 || c == 0) ? 0 : ((r - 1) * 4 + c); }

__device__ __forceinline__ unsigned short f2bf(float x) {
    __hip_bfloat16 h = __float2bfloat16(x);
    return *reinterpret_cast<unsigned short*>(&h);
}
__device__ __forceinline__ float bfu2f(unsigned short u) {
    __hip_bfloat16 h;
    *reinterpret_cast<unsigned short*>(&h) = u;
    return __bfloat162float(h);
}

// ---------------------------------------------------------------- setup
__global__ __launch_bounds__(256) void k_setup(
    const void* __restrict__ b_seq_r, const void* __restrict__ mask_r,
    const float* __restrict__ al1, const float* __restrict__ al2,
    int* __restrict__ maskI, int* __restrict__ perm, int* __restrict__ rowc,
    int* __restrict__ startPad, int* __restrict__ maskP,
    float* __restrict__ sm1, float* __restrict__ sm2)
{
    __shared__ int sf[2];
    __shared__ int cnts[BQ][NSEL];
    __shared__ int offs[BQ][NSEL];
    __shared__ int sstart[BQ][NSEL + 1];
    int tid = threadIdx.x;
    if (tid < BQ * NSEL) { cnts[tid / NSEL][tid % NSEL] = 0; offs[tid / NSEL][tid % NSEL] = 0; }
    if (tid == 0) {
        const int* b32 = (const int*)b_seq_r;
        int oddnz = 0, evennz = 0;
        for (int i = 0; i < 64; i++) { if (b32[2 * i + 1] != 0) oddnz++; if (b32[2 * i] != 0) evennz++; }
        sf[0] = (oddnz == 0 && evennz > 0) ? 1 : 0;
        const unsigned char* mb = (const unsigned char*)mask_r;
        int bytenz = 0;
        for (int i = 0; i < 256; i++) if ((i & 3) != 0 && mb[i] != 0) bytenz++;
        if (bytenz > 0) sf[1] = 1;
        else {
            const int* m32 = (const int*)mask_r;
            int onz = 0, enz = 0;
            for (int i = 0; i < 64; i++) { if (m32[2 * i + 1] != 0) onz++; if (m32[2 * i] != 0) enz++; }
            sf[1] = (onz == 0 && enz > 0) ? 2 : 0;
        }
    }
    __syncthreads();
    int bsI64 = sf[0], mk = sf[1];
    const int* b32 = (const int*)b_seq_r;
    const unsigned char* mb = (const unsigned char*)mask_r;
    const int* m32 = (const int*)mask_r;

    for (int g = tid; g < BQ * NN; g += 256) {
        int m = (mk == 1) ? (mb[g] != 0) : ((mk == 2) ? (m32[2 * g] != 0) : (m32[g] != 0));
        maskI[g] = m;
        int bs = bsI64 ? b32[2 * g] : b32[g];
        bs = bs < 0 ? 0 : (bs > 4 ? 4 : bs);
        atomicAdd(&cnts[g / NN][bs], 1);
    }
    __syncthreads();
    if (tid == 0) {
        for (int b = 0; b < BQ; b++) {
            int acc = 0;
            for (int c = 0; c < NSEL; c++) {
                sstart[b][c] = acc;
                acc += ((cnts[b][c] + 63) / 64) * 64;
            }
            sstart[b][NSEL] = acc;
            for (int c = 0; c <= NSEL; c++) startPad[b * (NSEL + 1) + c] = sstart[b][c];
        }
    }
    __syncthreads();
    for (int g = tid; g < BQ * NP; g += 256) {
        perm[g] = -1;
        int b = g / NP, sslot = g % NP;
        int c = 0;
        for (int cc = 1; cc < NSEL; cc++) if (sslot >= sstart[b][cc]) c = cc;
        rowc[g] = c;
    }
    __syncthreads();
    for (int g = tid; g < BQ * NN; g += 256) {
        int b = g / NN, n = g % NN;
        int bs = bsI64 ? b32[2 * g] : b32[g];
        bs = bs < 0 ? 0 : (bs > 4 ? 4 : bs);
        int pos = sstart[b][bs] + atomicAdd(&offs[b][bs], 1);
        perm[b * NP + pos] = n;
    }
    __syncthreads();
    // permuted mask: 2 = padding slot, else mask of the token
    for (int g = tid; g < BQ * NP; g += 256) {
        int tok = perm[g];
        maskP[g] = (tok < 0) ? 2 : maskI[(g / NP) * NN + tok];
    }
    // alpha softmaxes over the 4 blocks
    for (int p = tid; p < 2 * NCLS * NH; p += 256) {
        int w = p / (NCLS * NH);
        int rem = p % (NCLS * NH);
        int c = rem / NH, h = rem % NH;
        const float* a = w ? al2 : al1;
        float vals[4], mx = -1e30f;
        for (int bb = 0; bb < 4; bb++) { vals[bb] = a[(c * 4 + bb) * NH + h]; mx = fmaxf(mx, vals[bb]); }
        float ssum = 0.f;
        for (int bb = 0; bb < 4; bb++) { vals[bb] = expf(vals[bb] - mx); ssum += vals[bb]; }
        float inv = 1.0f / ssum;
        float* dst = w ? sm2 : sm1;
        for (int bb = 0; bb < 4; bb++) dst[(c * 4 + bb) * NH + h] = vals[bb] * inv;
    }
}

// ---------------------------------------------------------------- W mixing -> TRANSPOSED bf16
// W1bt[cls][h][n][m] = sum_B sm1[B]*W1[B][h][m][n]; W2bt[cls][h][k][d] likewise.
__global__ __launch_bounds__(256) void k_wmix(
    const float* __restrict__ W1, const float* __restrict__ W2,
    const float* __restrict__ sm1, const float* __restrict__ sm2,
    unsigned short* __restrict__ W1bt, unsigned short* __restrict__ W2bt)
{
    int bid = blockIdx.x;                 // 0..2*17*8-1
    int w = bid / (NCLS * NH);
    int rem = bid % (NCLS * NH);
    int c = rem / NH, h = rem % NH;
    const float* W = w ? W2 : W1;
    const float* sm = w ? sm2 : sm1;
    unsigned short* outp = (w ? W2bt : W1bt) + (((size_t)c * NH + h) << 12);
    float s0 = sm[(c * 4 + 0) * NH + h], s1 = sm[(c * 4 + 1) * NH + h];
    float s2 = sm[(c * 4 + 2) * NH + h], s3 = sm[(c * 4 + 3) * NH + h];
    const float* p0 = W + (size_t)(0 * NH + h) * 4096;
    const float* p1 = W + (size_t)(1 * NH + h) * 4096;
    const float* p2 = W + (size_t)(2 * NH + h) * 4096;
    const float* p3 = W + (size_t)(3 * NH + h) * 4096;
    for (int e = threadIdx.x; e < 4096; e += 256) {
        float v = s0 * p0[e] + s1 * p1[e] + s2 * p2[e] + s3 * p3[e];
        int mm = e >> 6, nn = e & 63;
        outp[nn * 64 + mm] = f2bf(v);     // transposed store
    }
}

// ---------------------------------------------------------------- bucketed QKV projection (f32 compute, bf16 out)
// grid (21 tiles, 4 hk-quarters, B*3), block 256. Tile: 64 permuted rows x 128 hk.
// t=0 -> Qb[b][h][ip][64], t=1 -> Kb[b][h][ip][64], t=2 -> Vt[b][h][d][ip] (transposed)
__global__ __launch_bounds__(256) void k_proj(
    const float* __restrict__ qr, const float* __restrict__ kr, const float* __restrict__ vr,
    const float* __restrict__ lr,
    const int* __restrict__ perm, const int* __restrict__ rowc, const int* __restrict__ startPad,
    unsigned short* __restrict__ Qb, unsigned short* __restrict__ Kb, unsigned short* __restrict__ Vt)
{
    int ti = blockIdx.x;
    int qtr = blockIdx.y;
    int bt = blockIdx.z;
    int b = bt / 3, t = bt % 3;
    int nTot = startPad[b * (NSEL + 1) + NSEL];
    if (ti * 64 >= nTot) return;
    int sel = rowc[b * NP + ti * 64];     // uniform per 64-tile by construction
    const float* X = (t == 0) ? qr : ((t == 1) ? kr : vr);
    const float* L = lr + ((size_t)t * NSEL + sel) * DMD * 512;

    __shared__ __align__(16) char smem[33280];
    float (*Xs)[36]  = (float (*)[36])smem;                    // 64x36 = 9216 B
    float (*Ls)[128] = (float (*)[128])(smem + 9216);          // 32x128 = 16384 B
    float (*Ts)[65]  = (float (*)[65])smem;                    // alias, used after compute
    __shared__ int toks[64];

    int tid = threadIdx.x;
    int tr = tid >> 5, tc = tid & 31;
    if (tid < 64) toks[tid] = perm[b * NP + ti * 64 + tid];
    float acc[8][4];
#pragma unroll
    for (int rr = 0; rr < 8; rr++) { acc[rr][0] = 0; acc[rr][1] = 0; acc[rr][2] = 0; acc[rr][3] = 0; }
    __syncthreads();

    for (int d0 = 0; d0 < DMD; d0 += 32) {
#pragma unroll
        for (int i = 0; i < 2; i++) {
            int fidx = tid + i * 256;
            int row = fidx >> 3, q4 = fidx & 7;
            int tok = toks[row];
            float4 val = make_float4(0.f, 0.f, 0.f, 0.f);
            if (tok >= 0) val = *(const float4*)&X[((size_t)b * NN + tok) * DMD + d0 + q4 * 4];
            *(float4*)&Xs[row][q4 * 4] = val;
        }
#pragma unroll
        for (int i = 0; i < 4; i++) {
            int fidx = tid + i * 256;
            int dd = fidx >> 5, c4 = fidx & 31;
            *(float4*)&Ls[dd][c4 * 4] =
                *(const float4*)&L[(size_t)(d0 + dd) * 512 + qtr * 128 + c4 * 4];
        }
        __syncthreads();
#pragma unroll 2
        for (int dd = 0; dd < 32; dd++) {
            float4 lv = *(const float4*)&Ls[dd][tc * 4];
#pragma unroll
            for (int rr = 0; rr < 8; rr++) {
                float xv = Xs[tr * 8 + rr][dd];
                acc[rr][0] += xv * lv.x; acc[rr][1] += xv * lv.y;
                acc[rr][2] += xv * lv.z; acc[rr][3] += xv * lv.w;
            }
        }
        __syncthreads();
    }

    if (t == 2) {
        // transpose through LDS, write Vt[b][h][d][ip] bf16
#pragma unroll
        for (int rr = 0; rr < 8; rr++)
#pragma unroll
            for (int cc = 0; cc < 4; cc++)
                Ts[tc * 4 + cc][tr * 8 + rr] = acc[rr][cc];
        __syncthreads();
#pragma unroll
        for (int i = 0; i < 32; i++) {
            int idx = tid + i * 256;           // 8192 = 128 hk x 64 ip
            int ip = idx & 63, hkl = idx >> 6;
            int hk = qtr * 128 + hkl;
            int h = hk >> 6, k = hk & 63;
            Vt[(((size_t)b * NH + h) * DKK + k) * NP + ti * 64 + ip] = f2bf(Ts[hkl][ip]);
        }
    } else {
        unsigned short* O = (t == 0) ? Qb : Kb;
#pragma unroll
        for (int rr = 0; rr < 8; rr++) {
            int ip = ti * 64 + tr * 8 + rr;
            int hk0 = qtr * 128 + tc * 4;
            int h = hk0 >> 6, k0 = hk0 & 63;
            ushort4 o4;
            o4.x = f2bf(acc[rr][0]); o4.y = f2bf(acc[rr][1]);
            o4.z = f2bf(acc[rr][2]); o4.w = f2bf(acc[rr][3]);
            *(ushort4*)&O[(((size_t)b * NH + h) * NP + ip) * 64 + k0] = o4;
        }
    }
}

// ---------------------------------------------------------------- fused attention, MFMA
// grid (NP/16, B*H), block 256 (4 waves). 16 query rows per block (bucket-uniform).
#define SS 1352   // S row stride (pad 8 -> 2-way bank aliasing, free)
__global__ __launch_bounds__(256, 2) void k_attn(
    const unsigned short* __restrict__ Qb, const unsigned short* __restrict__ Kb,
    const unsigned short* __restrict__ Vt,
    const unsigned short* __restrict__ W1bt, const unsigned short* __restrict__ W2bt,
    const int* __restrict__ perm, const int* __restrict__ rowc, const int* __restrict__ startPad,
    const int* __restrict__ maskI, const int* __restrict__ maskP,
    float* __restrict__ out)
{
    int it = blockIdx.x;
    int bh = blockIdx.y;
    int b = bh >> 3, h = bh & 7;
    int nTot = startPad[b * (NSEL + 1) + NSEL];
    int i0 = it * 16;
    if (i0 >= nTot) return;
    int r = rowc[b * NP + i0];
    int tiles = nTot >> 6;

    __shared__ unsigned short S[16][SS];              // 43264 B: scores then P (bf16)
    __shared__ __align__(16) unsigned short uqu[NSEL * 16 * 64];  // 10240 B: qloc, then u
    __shared__ int tilec[NPT];
    __shared__ int cstart[NSEL + 1];
    __shared__ int mrow[16];
    __shared__ int toki[16];
    __shared__ float sinv[16];

    int tid = threadIdx.x;
    int wave = tid >> 6, lane = tid & 63;
    int m = lane & 15, q = lane >> 4;

    const int* permB = perm + b * NP;
    const unsigned short* QbB = Qb + (size_t)bh * NP * 64;
    const unsigned short* KbB = Kb + (size_t)bh * NP * 64;
    const unsigned short* VtB = Vt + (size_t)bh * DKK * NP;
    const int* maskPB = maskP + b * NP;

    if (tid < NPT) tilec[tid] = rowc[b * NP + tid * 64];
    else if (tid >= 32 && tid < 32 + NSEL + 1) cstart[tid - 32] = startPad[b * (NSEL + 1) + (tid - 32)];
    else if (tid >= 64 && tid < 80) {
        int rr = tid - 64;
        int tok = permB[i0 + rr];
        toki[rr] = tok;
        mrow[rr] = (tok >= 0) ? maskI[b * NN + tok] : 0;
    }
    __syncthreads();

    // ---- phase 0b: qloc[c][i][n] = (Q . W1m[cls(r,c)]) via MFMA; wave owns n-subtile
    {
        const unsigned short* qa = &QbB[(size_t)(i0 + m) * 64 + q * 8];
        bf16x8 a0 = *(const bf16x8*)qa;
        bf16x8 a1 = *(const bf16x8*)(qa + 32);
        for (int c = 0; c < NSEL; c++) {
            int cls = clsOf(r, c);
            const unsigned short* wb = W1bt + (((size_t)cls * NH + h) << 12)
                                     + (size_t)(wave * 16 + m) * 64 + q * 8;
            bf16x8 b0 = *(const bf16x8*)wb;
            bf16x8 b1 = *(const bf16x8*)(wb + 32);
            f32x4 acc = {0.f, 0.f, 0.f, 0.f};
            acc = __builtin_amdgcn_mfma_f32_16x16x32_bf16(a0, b0, acc, 0, 0, 0);
            acc = __builtin_amdgcn_mfma_f32_16x16x32_bf16(a1, b1, acc, 0, 0, 0);
#pragma unroll
            for (int g = 0; g < 4; g++) {
                int i = q * 4 + g;
                uqu[(c * 16 + i) * 64 + wave * 16 + m] = f2bf(acc[g]);
            }
        }
    }
    __syncthreads();

    // ---- phase 1: scores; waves split key tiles
    for (int jt = wave; jt < tiles; jt += 4) {
        int c = tilec[jt];
        int jb = jt * 64;
        const unsigned short* qa = &uqu[(size_t)(c * 16 + m) * 64 + q * 8];
        bf16x8 a0 = *(const bf16x8*)qa;
        bf16x8 a1 = *(const bf16x8*)(qa + 32);
#pragma unroll
        for (int nb = 0; nb < 4; nb++) {
            int j = jb + nb * 16 + m;
            const unsigned short* kb = &KbB[(size_t)j * 64 + q * 8];
            bf16x8 b0 = *(const bf16x8*)kb;
            bf16x8 b1 = *(const bf16x8*)(kb + 32);
            f32x4 acc = {0.f, 0.f, 0.f, 0.f};
            acc = __builtin_amdgcn_mfma_f32_16x16x32_bf16(a0, b0, acc, 0, 0, 0);
            acc = __builtin_amdgcn_mfma_f32_16x16x32_bf16(a1, b1, acc, 0, 0, 0);
            int mj = maskPB[j];
#pragma unroll
            for (int g = 0; g < 4; g++) {
                int i = q * 4 + g;
                float sv;
                if (mj == 2)            sv = -INFINITY;       // padding slot
                else if (mrow[i] && mj) sv = acc[g] * 0.125f;
                else                    sv = -1e30f;          // reference's masked value
                S[i][j] = f2bf(sv);
            }
        }
    }
    __syncthreads();

    // ---- phase 2: softmax (unnormalized P; 1/sum deferred to epilogue)
    for (int rr = wave * 4; rr < wave * 4 + 4; rr++) {
        float mx = -INFINITY;
        for (int j = lane; j < nTot; j += 64) mx = fmaxf(mx, bfu2f(S[rr][j]));
        for (int o = 32; o > 0; o >>= 1) mx = fmaxf(mx, __shfl_xor(mx, o));
        float sum = 0.f;
        for (int j = lane; j < nTot; j += 64) {
            float e = __expf(bfu2f(S[rr][j]) - mx);
            sum += e;
            S[rr][j] = f2bf(e);
        }
        for (int o = 32; o > 0; o >>= 1) sum += __shfl_xor(sum, o);
        if (lane == 0) sinv[rr] = 1.0f / sum;
    }
    __syncthreads();

    // ---- phase 3: PV per class (contiguous tile ranges); wave owns d-subtile
    {
        int db = wave * 16;
        for (int c = 0; c < NSEL; c++) {
            int ct0 = cstart[c] >> 6, ct1 = cstart[c + 1] >> 6;
            f32x4 acc = {0.f, 0.f, 0.f, 0.f};
            for (int jt = ct0; jt < ct1; jt++) {
                int jb = jt * 64;
                bf16x8 a0 = *(const bf16x8*)&S[m][jb + q * 8];
                bf16x8 a1 = *(const bf16x8*)&S[m][jb + 32 + q * 8];
                const unsigned short* vb = &VtB[(size_t)(db + m) * NP + jb + q * 8];
                bf16x8 b0 = *(const bf16x8*)vb;
                bf16x8 b1 = *(const bf16x8*)(vb + 32);
                acc = __builtin_amdgcn_mfma_f32_16x16x32_bf16(a0, b0, acc, 0, 0, 0);
                acc = __builtin_amdgcn_mfma_f32_16x16x32_bf16(a1, b1, acc, 0, 0, 0);
            }
#pragma unroll
            for (int g = 0; g < 4; g++) {
                int i = q * 4 + g;
                uqu[(c * 16 + i) * 64 + db + m] = f2bf(acc[g]);
            }
        }
    }
    __syncthreads();

    // ---- phase 4: out = (sum_c u[c] . W2m[cls(r,c)]) * sinv ; wave owns k-subtile
    {
        f32x4 acc = {0.f, 0.f, 0.f, 0.f};
        for (int c = 0; c < NSEL; c++) {
            int cls = clsOf(r, c);
            const unsigned short* ua = &uqu[(size_t)(c * 16 + m) * 64 + q * 8];
            bf16x8 a0 = *(const bf16x8*)ua;
            bf16x8 a1 = *(const bf16x8*)(ua + 32);
            const unsigned short* wb = W2bt + (((size_t)cls * NH + h) << 12)
                                     + (size_t)(wave * 16 + m) * 64 + q * 8;
            bf16x8 b0 = *(const bf16x8*)wb;
            bf16x8 b1 = *(const bf16x8*)(wb + 32);
            acc = __builtin_amdgcn_mfma_f32_16x16x32_bf16(a0, b0, acc, 0, 0, 0);
            acc = __builtin_amdgcn_mfma_f32_16x16x32_bf16(a1, b1, acc, 0, 0, 0);
        }
#pragma unroll
        for (int g = 0; g < 4; g++) {
            int i = q * 4 + g;
            int tok = toki[i];
            if (tok >= 0)
                out[((size_t)b * NN + tok) * (NH * DKK) + h * DKK + wave * 16 + m] = acc[g] * sinv[i];
        }
    }
}

// ---------------------------------------------------------------- launch
extern "C" void kernel_launch(void* const* d_in, const int* in_sizes, int n_in,
                              void* d_out, int out_size, void* d_ws, size_t ws_size,
                              hipStream_t stream)
{
    const float* qr  = (const float*)d_in[0];
    const float* kr  = (const float*)d_in[1];
    const float* vr  = (const float*)d_in[2];
    const void* bsr  = d_in[3];
    const void* mkr  = d_in[4];
    const float* lr  = (const float*)d_in[5];
    const float* w1r = (const float*)d_in[6];
    const float* a1r = (const float*)d_in[7];
    const float* w2r = (const float*)d_in[8];
    const float* a2r = (const float*)d_in[9];
    float* out = (float*)d_out;   // reference output dtype is float32

    char* w = (char*)d_ws;
    int* maskI    = (int*)w;                       // 2048 ints
    int* perm     = maskI + BQ * NN;               // 2688 ints
    int* rowc     = perm + BQ * NP;                // 2688 ints
    int* startPad = rowc + BQ * NP;                // 12 ints
    int* maskP    = startPad + 12;                 // 2688 ints
    float* sm1 = (float*)(w + 65536);
    float* sm2 = sm1 + NCLS * 4 * NH;
    unsigned short* W1bt = (unsigned short*)(w + 131072);            // 17*8*4096 = 557056 els
    unsigned short* W2bt = W1bt + (size_t)NCLS * NH * 4096;
    unsigned short* Qb   = (unsigned short*)(w + 2359296);           // each 2*8*1344*64 els
    unsigned short* Kb   = Qb + (size_t)BQ * NH * NP * 64;
    unsigned short* Vt   = Kb + (size_t)BQ * NH * NP * 64;
    // total ws use: ~10.6 MB

    hipLaunchKernelGGL(k_setup, dim3(1), dim3(256), 0, stream,
                       bsr, mkr, a1r, a2r, maskI, perm, rowc, startPad, maskP, sm1, sm2);
    hipLaunchKernelGGL(k_wmix, dim3(2 * NCLS * NH), dim3(256), 0, stream,
                       w1r, w2r, sm1, sm2, W1bt, W2bt);
    hipLaunchKernelGGL(k_proj, dim3(NPT, 4, 6), dim3(256), 0, stream,
                       qr, kr, vr, lr, perm, rowc, startPad, Qb, Kb, Vt);
    hipLaunchKernelGGL(k_attn, dim3(NP / 16, BQ * NH), dim3(256), 0, stream,
                       Qb, Kb, Vt, W1bt, W2bt, perm, rowc, startPad, maskI, maskP, out);
}

// Round 6
// 206.628 us; speedup vs baseline: 5.8950x; 1.4291x over previous
//
#include <hip/hip_runtime.h>
#include <hip/hip_bf16.h>
#include <math.h>

#define BQ   2      // batch
#define NN   1024   // seq len
#define DMD  512    // d_model
#define NH   8      // heads
#define DKK  64     // head dim
#define NSEL 5      // NB+1 block values (0..4)
#define NCLS 17     // block-pair classes
#define NP   1344   // padded per-batch capacity (buckets padded to 64)
#define NPT  21     // NP/64 tiles
#define MAXT 6      // max key-tiles per wave in k_attn (ceil(21/4))

typedef __attribute__((ext_vector_type(8))) short bf16x8;
typedef __attribute__((ext_vector_type(8))) unsigned short u16x8;
typedef __attribute__((ext_vector_type(4))) float f32x4;

__device__ __forceinline__ int clsOf(int r, int c) { return (r == 0 || c == 0) ? 0 : ((r - 1) * 4 + c); }

__device__ __forceinline__ unsigned short f2bf(float x) {
    __hip_bfloat16 h = __float2bfloat16(x);
    return *reinterpret_cast<unsigned short*>(&h);
}

// ---------------------------------------------------------------- setup
__global__ __launch_bounds__(256) void k_setup(
    const void* __restrict__ b_seq_r, const void* __restrict__ mask_r,
    const float* __restrict__ al1, const float* __restrict__ al2,
    int* __restrict__ maskI, int* __restrict__ perm, int* __restrict__ rowc,
    int* __restrict__ startPad, int* __restrict__ maskP,
    float* __restrict__ sm1, float* __restrict__ sm2)
{
    __shared__ int det[5];
    __shared__ int cnts[BQ][NSEL];
    __shared__ int offs[BQ][NSEL];
    __shared__ int sstart[BQ][NSEL + 1];
    int tid = threadIdx.x;
    if (tid < 5) det[tid] = 0;
    if (tid < BQ * NSEL) { cnts[tid / NSEL][tid % NSEL] = 0; offs[tid / NSEL][tid % NSEL] = 0; }
    __syncthreads();
    // parallel dtype detection
    const int* b32 = (const int*)b_seq_r;
    const unsigned char* mb = (const unsigned char*)mask_r;
    const int* m32 = (const int*)mask_r;
    if (tid < 64) {
        if (b32[2 * tid + 1] != 0) atomicOr(&det[0], 1);
        if (b32[2 * tid] != 0)     atomicOr(&det[1], 1);
        if (m32[2 * tid + 1] != 0) atomicOr(&det[3], 1);
        if (m32[2 * tid] != 0)     atomicOr(&det[4], 1);
    }
    if ((tid & 3) != 0 && mb[tid] != 0) atomicOr(&det[2], 1);
    __syncthreads();
    int bsI64 = (det[0] == 0 && det[1] != 0);
    int mk = det[2] ? 1 : ((det[3] == 0 && det[4] != 0) ? 2 : 0);

    for (int g = tid; g < BQ * NN; g += 256) {
        int m = (mk == 1) ? (mb[g] != 0) : ((mk == 2) ? (m32[2 * g] != 0) : (m32[g] != 0));
        maskI[g] = m;
        int bs = bsI64 ? b32[2 * g] : b32[g];
        bs = bs < 0 ? 0 : (bs > 4 ? 4 : bs);
        atomicAdd(&cnts[g / NN][bs], 1);
    }
    __syncthreads();
    if (tid == 0) {
        for (int b = 0; b < BQ; b++) {
            int acc = 0;
            for (int c = 0; c < NSEL; c++) {
                sstart[b][c] = acc;
                acc += ((cnts[b][c] + 63) / 64) * 64;
            }
            sstart[b][NSEL] = acc;
            for (int c = 0; c <= NSEL; c++) startPad[b * (NSEL + 1) + c] = sstart[b][c];
        }
    }
    __syncthreads();
    for (int g = tid; g < BQ * NP; g += 256) {
        perm[g] = -1;
        int b = g / NP, sslot = g % NP;
        int c = 0;
        for (int cc = 1; cc < NSEL; cc++) if (sslot >= sstart[b][cc]) c = cc;
        rowc[g] = c;
    }
    __syncthreads();
    for (int g = tid; g < BQ * NN; g += 256) {
        int b = g / NN, n = g % NN;
        int bs = bsI64 ? b32[2 * g] : b32[g];
        bs = bs < 0 ? 0 : (bs > 4 ? 4 : bs);
        int pos = sstart[b][bs] + atomicAdd(&offs[b][bs], 1);
        perm[b * NP + pos] = n;
    }
    __syncthreads();
    // permuted mask: 2 = padding slot, else mask of the token
    for (int g = tid; g < BQ * NP; g += 256) {
        int tok = perm[g];
        maskP[g] = (tok < 0) ? 2 : maskI[(g / NP) * NN + tok];
    }
    // alpha softmaxes over the 4 blocks
    for (int p = tid; p < 2 * NCLS * NH; p += 256) {
        int w = p / (NCLS * NH);
        int rem = p % (NCLS * NH);
        int c = rem / NH, h = rem % NH;
        const float* a = w ? al2 : al1;
        float vals[4], mx = -1e30f;
        for (int bb = 0; bb < 4; bb++) { vals[bb] = a[(c * 4 + bb) * NH + h]; mx = fmaxf(mx, vals[bb]); }
        float ssum = 0.f;
        for (int bb = 0; bb < 4; bb++) { vals[bb] = expf(vals[bb] - mx); ssum += vals[bb]; }
        float inv = 1.0f / ssum;
        float* dst = w ? sm2 : sm1;
        for (int bb = 0; bb < 4; bb++) dst[(c * 4 + bb) * NH + h] = vals[bb] * inv;
    }
}

// ---------------------------------------------------------------- cast+transpose lin -> Lt bf16 [t*5+sel][n][k]
__global__ __launch_bounds__(256) void k_cast(
    const float* __restrict__ lr, unsigned short* __restrict__ Lt)
{
    int kt = blockIdx.x, nt = blockIdx.y, ts = blockIdx.z;   // 8,8,15
    const float* src = lr + (size_t)ts * DMD * 512;
    unsigned short* dst = Lt + (size_t)ts * DMD * 512;
    __shared__ float Tf[64][68];
    int tid = threadIdx.x;
    int r = tid >> 2, c4 = tid & 3;
#pragma unroll
    for (int i = 0; i < 4; i++) {
        float4 v = *(const float4*)&src[(size_t)(kt * 64 + r) * 512 + nt * 64 + c4 * 16 + i * 4];
        *(float4*)&Tf[r][c4 * 16 + i * 4] = v;
    }
    __syncthreads();
    unsigned short tmp[16];
#pragma unroll
    for (int i = 0; i < 16; i++) tmp[i] = f2bf(Tf[c4 * 16 + i][r]);
    u16x8 o0, o1;
#pragma unroll
    for (int i = 0; i < 8; i++) { o0[i] = tmp[i]; o1[i] = tmp[8 + i]; }
    unsigned short* dp = &dst[(size_t)(nt * 64 + r) * 512 + kt * 64 + c4 * 16];
    *(u16x8*)&dp[0] = o0;
    *(u16x8*)&dp[8] = o1;
}

// ---------------------------------------------------------------- W mixing -> TRANSPOSED bf16
__global__ __launch_bounds__(256) void k_wmix(
    const float* __restrict__ W1, const float* __restrict__ W2,
    const float* __restrict__ sm1, const float* __restrict__ sm2,
    unsigned short* __restrict__ W1bt, unsigned short* __restrict__ W2bt)
{
    int bid = blockIdx.x;                 // 0..2*17*8-1
    int w = bid / (NCLS * NH);
    int rem = bid % (NCLS * NH);
    int c = rem / NH, h = rem % NH;
    const float* W = w ? W2 : W1;
    const float* sm = w ? sm2 : sm1;
    unsigned short* outp = (w ? W2bt : W1bt) + (((size_t)c * NH + h) << 12);
    float s0 = sm[(c * 4 + 0) * NH + h], s1 = sm[(c * 4 + 1) * NH + h];
    float s2 = sm[(c * 4 + 2) * NH + h], s3 = sm[(c * 4 + 3) * NH + h];
    const float* p0 = W + (size_t)(0 * NH + h) * 4096;
    const float* p1 = W + (size_t)(1 * NH + h) * 4096;
    const float* p2 = W + (size_t)(2 * NH + h) * 4096;
    const float* p3 = W + (size_t)(3 * NH + h) * 4096;
    for (int e = threadIdx.x; e < 4096; e += 256) {
        float v = s0 * p0[e] + s1 * p1[e] + s2 * p2[e] + s3 * p3[e];
        int mm = e >> 6, nn = e & 63;
        outp[nn * 64 + mm] = f2bf(v);     // transposed store
    }
}

// ---------------------------------------------------------------- bucketed QKV projection, MFMA bf16
// grid (21 tiles, 4 hk-quarters, B*3), block 256. Tile: 64 rows x 128 hk x 512 K.
__global__ __launch_bounds__(256) void k_proj(
    const float* __restrict__ qr, const float* __restrict__ kr, const float* __restrict__ vr,
    const unsigned short* __restrict__ Lt,
    const int* __restrict__ perm, const int* __restrict__ rowc, const int* __restrict__ startPad,
    unsigned short* __restrict__ Qb, unsigned short* __restrict__ Kb, unsigned short* __restrict__ Vt)
{
    int ti = blockIdx.x;
    int qtr = blockIdx.y;
    int bt = blockIdx.z;
    int b = bt / 3, t = bt % 3;
    int nTot = startPad[b * (NSEL + 1) + NSEL];
    if (ti * 64 >= nTot) return;
    int sel = rowc[b * NP + ti * 64];
    const float* X = (t == 0) ? qr : ((t == 1) ? kr : vr);
    const unsigned short* L = Lt + (size_t)(t * NSEL + sel) * DMD * 512;   // [n][k] bf16

    __shared__ __align__(16) unsigned short Xb[64][72];    // 9216 B
    __shared__ __align__(16) unsigned short Lb[128][72];   // 18432 B (reused as transpose buf for t==2)
    __shared__ int toks[64];

    int tid = threadIdx.x;
    int wave = tid >> 6, lane = tid & 63;
    int m = lane & 15, q = lane >> 4;
    if (tid < 64) toks[tid] = perm[b * NP + ti * 64 + tid];
    f32x4 acc[4][2];
#pragma unroll
    for (int mt = 0; mt < 4; mt++) { acc[mt][0] = {0, 0, 0, 0}; acc[mt][1] = {0, 0, 0, 0}; }
    __syncthreads();

    for (int kb = 0; kb < DMD; kb += 64) {
        // stage Xb (f32 -> bf16): thread = (row, 16-col chunk)
        {
            int r = tid >> 2, c0 = (tid & 3) * 16;
            int tok = toks[r];
            unsigned short tmp[16];
            if (tok >= 0) {
                const float* xp = &X[((size_t)b * NN + tok) * DMD + kb + c0];
#pragma unroll
                for (int i = 0; i < 16; i += 4) {
                    float4 v = *(const float4*)&xp[i];
                    tmp[i] = f2bf(v.x); tmp[i + 1] = f2bf(v.y);
                    tmp[i + 2] = f2bf(v.z); tmp[i + 3] = f2bf(v.w);
                }
            } else {
#pragma unroll
                for (int i = 0; i < 16; i++) tmp[i] = 0;
            }
            u16x8 o0, o1;
#pragma unroll
            for (int i = 0; i < 8; i++) { o0[i] = tmp[i]; o1[i] = tmp[8 + i]; }
            *(u16x8*)&Xb[r][c0] = o0;
            *(u16x8*)&Xb[r][c0 + 8] = o1;
        }
        // stage Lb (bf16 direct): thread = (n-row, 32-col half)
        {
            int n = tid >> 1, hf = tid & 1;
            const unsigned short* lp = &L[(size_t)(qtr * 128 + n) * 512 + kb + hf * 32];
#pragma unroll
            for (int s = 0; s < 4; s++)
                *(u16x8*)&Lb[n][hf * 32 + s * 8] = *(const u16x8*)&lp[s * 8];
        }
        __syncthreads();
#pragma unroll
        for (int kc = 0; kc < 64; kc += 32) {
            bf16x8 bf0 = *(const bf16x8*)&Lb[wave * 32 + m][kc + q * 8];
            bf16x8 bf1 = *(const bf16x8*)&Lb[wave * 32 + 16 + m][kc + q * 8];
#pragma unroll
            for (int mt = 0; mt < 4; mt++) {
                bf16x8 a = *(const bf16x8*)&Xb[mt * 16 + m][kc + q * 8];
                acc[mt][0] = __builtin_amdgcn_mfma_f32_16x16x32_bf16(a, bf0, acc[mt][0], 0, 0, 0);
                acc[mt][1] = __builtin_amdgcn_mfma_f32_16x16x32_bf16(a, bf1, acc[mt][1], 0, 0, 0);
            }
        }
        __syncthreads();
    }

    if (t < 2) {
        unsigned short* O = (t == 0) ? Qb : Kb;
#pragma unroll
        for (int mt = 0; mt < 4; mt++)
#pragma unroll
            for (int nt = 0; nt < 2; nt++)
#pragma unroll
                for (int g = 0; g < 4; g++) {
                    int i = mt * 16 + q * 4 + g;
                    int hk = qtr * 128 + wave * 32 + nt * 16 + m;
                    int h = hk >> 6, k0 = hk & 63;
                    O[(((size_t)b * NH + h) * NP + ti * 64 + i) * 64 + k0] = f2bf(acc[mt][nt][g]);
                }
    } else {
        // transpose via LDS (Lb reused), then coalesced Vt[b][h][d][ip] writes
#pragma unroll
        for (int mt = 0; mt < 4; mt++)
#pragma unroll
            for (int nt = 0; nt < 2; nt++)
#pragma unroll
                for (int g = 0; g < 4; g++)
                    Lb[wave * 32 + nt * 16 + m][mt * 16 + q * 4 + g] = f2bf(acc[mt][nt][g]);
        __syncthreads();
        int jl = tid >> 1, hf = tid & 1;
        int hk = qtr * 128 + jl;
        int h = hk >> 6, d = hk & 63;
        unsigned short* vp = Vt + (((size_t)b * NH + h) * DKK + d) * NP + ti * 64 + hf * 32;
#pragma unroll
        for (int s = 0; s < 4; s++)
            *(u16x8*)&vp[s * 8] = *(const u16x8*)&Lb[jl][hf * 32 + s * 8];
    }
}

// ---------------------------------------------------------------- fused attention, MFMA + register scores
#define SS 1352   // S row stride in shorts
__global__ __launch_bounds__(256, 2) void k_attn(
    const unsigned short* __restrict__ Qb, const unsigned short* __restrict__ Kb,
    const unsigned short* __restrict__ Vt,
    const unsigned short* __restrict__ W1bt, const unsigned short* __restrict__ W2bt,
    const int* __restrict__ perm, const int* __restrict__ rowc, const int* __restrict__ startPad,
    const int* __restrict__ maskI, const int* __restrict__ maskP,
    float* __restrict__ out)
{
    int it = blockIdx.x;
    int bh = blockIdx.y;
    int b = bh >> 3, h = bh & 7;
    int nTot = startPad[b * (NSEL + 1) + NSEL];
    int i0 = it * 16;
    if (i0 >= nTot) return;
    int r = rowc[b * NP + i0];
    int tiles = nTot >> 6;

    __shared__ unsigned short S[16][SS];                          // 43264 B: P (bf16)
    __shared__ __align__(16) unsigned short uqu[NSEL * 16 * 64];  // 10240 B: qloc, then u
    __shared__ float wred[4][16];
    __shared__ float wsum[4][16];
    __shared__ int tilec[NPT];
    __shared__ int cstart[NSEL + 1];
    __shared__ int mrow[16];
    __shared__ int toki[16];

    int tid = threadIdx.x;
    int wave = tid >> 6, lane = tid & 63;
    int m = lane & 15, q = lane >> 4;

    const int* permB = perm + b * NP;
    const unsigned short* QbB = Qb + (size_t)bh * NP * 64;
    const unsigned short* KbB = Kb + (size_t)bh * NP * 64;
    const unsigned short* VtB = Vt + (size_t)bh * DKK * NP;
    const int* maskPB = maskP + b * NP;

    if (tid < NPT) tilec[tid] = rowc[b * NP + tid * 64];
    else if (tid >= 32 && tid < 32 + NSEL + 1) cstart[tid - 32] = startPad[b * (NSEL + 1) + (tid - 32)];
    else if (tid >= 64 && tid < 80) {
        int rr = tid - 64;
        int tok = permB[i0 + rr];
        toki[rr] = tok;
        mrow[rr] = (tok >= 0) ? maskI[b * NN + tok] : 0;
    }
    __syncthreads();

    // ---- phase 0b: qloc[c][i][n] = Q . W1m[cls(r,c)] via MFMA; wave owns n-subtile
    {
        const unsigned short* qa = &QbB[(size_t)(i0 + m) * 64 + q * 8];
        bf16x8 a0 = *(const bf16x8*)qa;
        bf16x8 a1 = *(const bf16x8*)(qa + 32);
        for (int c = 0; c < NSEL; c++) {
            int cls = clsOf(r, c);
            const unsigned short* wb = W1bt + (((size_t)cls * NH + h) << 12)
                                     + (size_t)(wave * 16 + m) * 64 + q * 8;
            bf16x8 b0 = *(const bf16x8*)wb;
            bf16x8 b1 = *(const bf16x8*)(wb + 32);
            f32x4 acc = {0.f, 0.f, 0.f, 0.f};
            acc = __builtin_amdgcn_mfma_f32_16x16x32_bf16(a0, b0, acc, 0, 0, 0);
            acc = __builtin_amdgcn_mfma_f32_16x16x32_bf16(a1, b1, acc, 0, 0, 0);
#pragma unroll
            for (int g = 0; g < 4; g++)
                uqu[(c * 16 + q * 4 + g) * 64 + wave * 16 + m] = f2bf(acc[g]);
        }
    }
    __syncthreads();

    // ---- phase 1: scores in REGISTERS; per-lane row maxima
    float sarr[MAXT][4][4];
    float lmax[4] = {-INFINITY, -INFINITY, -INFINITY, -INFINITY};
    int mrow4[4];
#pragma unroll
    for (int g = 0; g < 4; g++) mrow4[g] = mrow[q * 4 + g];

#pragma unroll
    for (int tt = 0; tt < MAXT; tt++) {
        int jt = wave + tt * 4;
        bool valid = (jt < tiles);
        int jts = valid ? jt : 0;
        int c = tilec[jts];
        int jb = jts * 64;
        const unsigned short* qa = &uqu[(size_t)(c * 16 + m) * 64 + q * 8];
        bf16x8 a0 = *(const bf16x8*)qa;
        bf16x8 a1 = *(const bf16x8*)(qa + 32);
#pragma unroll
        for (int nb = 0; nb < 4; nb++) {
            int j = jb + nb * 16 + m;
            const unsigned short* kb = &KbB[(size_t)j * 64 + q * 8];
            bf16x8 b0 = *(const bf16x8*)kb;
            bf16x8 b1 = *(const bf16x8*)(kb + 32);
            f32x4 acc = {0.f, 0.f, 0.f, 0.f};
            acc = __builtin_amdgcn_mfma_f32_16x16x32_bf16(a0, b0, acc, 0, 0, 0);
            acc = __builtin_amdgcn_mfma_f32_16x16x32_bf16(a1, b1, acc, 0, 0, 0);
            int mj = maskPB[j];
#pragma unroll
            for (int g = 0; g < 4; g++) {
                float sv;
                if (!valid || mj == 2)  sv = -INFINITY;       // padding / no tile
                else if (mrow4[g] && mj) sv = acc[g] * 0.125f;
                else                     sv = -1e30f;         // reference's masked value
                sarr[tt][nb][g] = sv;
                lmax[g] = fmaxf(lmax[g], sv);
            }
        }
    }
    // reduce max over the 16 m-lanes of each q-group
#pragma unroll
    for (int g = 0; g < 4; g++) {
        float v = lmax[g];
#pragma unroll
        for (int o = 1; o < 16; o <<= 1) v = fmaxf(v, __shfl_xor(v, o));
        lmax[g] = v;
    }
    if (m == 0) {
#pragma unroll
        for (int g = 0; g < 4; g++) wred[wave][q * 4 + g] = lmax[g];
    }
    __syncthreads();

    // ---- phase 2: exp in registers, single P write, row sums
    float mx4[4], lsum[4] = {0.f, 0.f, 0.f, 0.f};
#pragma unroll
    for (int g = 0; g < 4; g++) {
        int i = q * 4 + g;
        mx4[g] = fmaxf(fmaxf(wred[0][i], wred[1][i]), fmaxf(wred[2][i], wred[3][i]));
    }
#pragma unroll
    for (int tt = 0; tt < MAXT; tt++) {
        int jt = wave + tt * 4;
        bool valid = (jt < tiles);
        int jb = jt * 64;
#pragma unroll
        for (int nb = 0; nb < 4; nb++) {
            int j = jb + nb * 16 + m;
#pragma unroll
            for (int g = 0; g < 4; g++) {
                float p = __expf(sarr[tt][nb][g] - mx4[g]);   // -inf -> 0
                lsum[g] += p;
                if (valid) S[q * 4 + g][j] = f2bf(p);
            }
        }
    }
#pragma unroll
    for (int g = 0; g < 4; g++) {
        float v = lsum[g];
#pragma unroll
        for (int o = 1; o < 16; o <<= 1) v += __shfl_xor(v, o);
        lsum[g] = v;
    }
    if (m == 0) {
#pragma unroll
        for (int g = 0; g < 4; g++) wsum[wave][q * 4 + g] = lsum[g];
    }
    __syncthreads();
    float sinv4[4];
#pragma unroll
    for (int g = 0; g < 4; g++) {
        int i = q * 4 + g;
        sinv4[g] = 1.0f / (wsum[0][i] + wsum[1][i] + wsum[2][i] + wsum[3][i]);
    }

    // ---- phase 3: PV per class (contiguous tiles); wave owns d-subtile; dual acc chains
    {
        int db = wave * 16;
        for (int c = 0; c < NSEL; c++) {
            int ct0 = cstart[c] >> 6, ct1 = cstart[c + 1] >> 6;
            f32x4 ae = {0.f, 0.f, 0.f, 0.f};
            f32x4 ao = {0.f, 0.f, 0.f, 0.f};
            for (int jt = ct0; jt < ct1; jt++) {
                int jb = jt * 64;
                bf16x8 a0 = *(const bf16x8*)&S[m][jb + q * 8];
                bf16x8 a1 = *(const bf16x8*)&S[m][jb + 32 + q * 8];
                const unsigned short* vb = &VtB[(size_t)(db + m) * NP + jb + q * 8];
                bf16x8 b0 = *(const bf16x8*)vb;
                bf16x8 b1 = *(const bf16x8*)(vb + 32);
                ae = __builtin_amdgcn_mfma_f32_16x16x32_bf16(a0, b0, ae, 0, 0, 0);
                ao = __builtin_amdgcn_mfma_f32_16x16x32_bf16(a1, b1, ao, 0, 0, 0);
            }
#pragma unroll
            for (int g = 0; g < 4; g++)
                uqu[(c * 16 + q * 4 + g) * 64 + db + m] = f2bf(ae[g] + ao[g]);
        }
    }
    __syncthreads();

    // ---- phase 4: out = (sum_c u[c] . W2m[cls(r,c)]) * sinv ; wave owns k-subtile
    {
        f32x4 acc = {0.f, 0.f, 0.f, 0.f};
        for (int c = 0; c < NSEL; c++) {
            int cls = clsOf(r, c);
            const unsigned short* ua = &uqu[(size_t)(c * 16 + m) * 64 + q * 8];
            bf16x8 a0 = *(const bf16x8*)ua;
            bf16x8 a1 = *(const bf16x8*)(ua + 32);
            const unsigned short* wb = W2bt + (((size_t)cls * NH + h) << 12)
                                     + (size_t)(wave * 16 + m) * 64 + q * 8;
            bf16x8 b0 = *(const bf16x8*)wb;
            bf16x8 b1 = *(const bf16x8*)(wb + 32);
            acc = __builtin_amdgcn_mfma_f32_16x16x32_bf16(a0, b0, acc, 0, 0, 0);
            acc = __builtin_amdgcn_mfma_f32_16x16x32_bf16(a1, b1, acc, 0, 0, 0);
        }
#pragma unroll
        for (int g = 0; g < 4; g++) {
            int i = q * 4 + g;
            int tok = toki[i];
            if (tok >= 0)
                out[((size_t)b * NN + tok) * (NH * DKK) + h * DKK + wave * 16 + m] = acc[g] * sinv4[g];
        }
    }
}

// ---------------------------------------------------------------- launch
extern "C" void kernel_launch(void* const* d_in, const int* in_sizes, int n_in,
                              void* d_out, int out_size, void* d_ws, size_t ws_size,
                              hipStream_t stream)
{
    const float* qr  = (const float*)d_in[0];
    const float* kr  = (const float*)d_in[1];
    const float* vr  = (const float*)d_in[2];
    const void* bsr  = d_in[3];
    const void* mkr  = d_in[4];
    const float* lr  = (const float*)d_in[5];
    const float* w1r = (const float*)d_in[6];
    const float* a1r = (const float*)d_in[7];
    const float* w2r = (const float*)d_in[8];
    const float* a2r = (const float*)d_in[9];
    float* out = (float*)d_out;   // reference output dtype is float32

    char* w = (char*)d_ws;
    int* maskI    = (int*)w;                       // 2048 ints
    int* perm     = maskI + BQ * NN;               // 2688 ints
    int* rowc     = perm + BQ * NP;                // 2688 ints
    int* startPad = rowc + BQ * NP;                // 12 ints
    int* maskP    = startPad + 12;                 // 2688 ints
    float* sm1 = (float*)(w + 65536);
    float* sm2 = sm1 + NCLS * 4 * NH;
    unsigned short* W1bt = (unsigned short*)(w + 131072);
    unsigned short* W2bt = W1bt + (size_t)NCLS * NH * 4096;
    unsigned short* Qb   = (unsigned short*)(w + 2359296);
    unsigned short* Kb   = Qb + (size_t)BQ * NH * NP * 64;
    unsigned short* Vt   = Kb + (size_t)BQ * NH * NP * 64;
    unsigned short* Lt   = Vt + (size_t)BQ * NH * NP * 64;   // 15*512*512 bf16
    // total ws use: ~18.5 MB

    hipLaunchKernelGGL(k_setup, dim3(1), dim3(256), 0, stream,
                       bsr, mkr, a1r, a2r, maskI, perm, rowc, startPad, maskP, sm1, sm2);
    hipLaunchKernelGGL(k_cast, dim3(8, 8, 15), dim3(256), 0, stream, lr, Lt);
    hipLaunchKernelGGL(k_wmix, dim3(2 * NCLS * NH), dim3(256), 0, stream,
                       w1r, w2r, sm1, sm2, W1bt, W2bt);
    hipLaunchKernelGGL(k_proj, dim3(NPT, 4, 6), dim3(256), 0, stream,
                       qr, kr, vr, Lt, perm, rowc, startPad, Qb, Kb, Vt);
    hipLaunchKernelGGL(k_attn, dim3(NP / 16, BQ * NH), dim3(256), 0, stream,
                       Qb, Kb, Vt, W1bt, W2bt, perm, rowc, startPad, maskI, maskP, out);
}